// Round 7
// baseline (25070.711 us; speedup 1.0000x reference)
//
#include <hip/hip_runtime.h>
#include <math.h>

// LSTMNN: T=1024, B=64, I=128, H=512, L=2, fp32. Persistent 256 WG x 512 thr.
// Round 11: keep R10's halved per-WG read volume; fix the write regression.
//   R10 post-mortem: WRITE_SIZE 0.45->3.75 GB while FETCH fell. The batch
//   split fragmented activation stores (waves wrote disjoint 128B runs of
//   [col][b=64] rows) -> sc0sc1 scalar stores stopped write-combining,
//   ~32B/store at the EA = +3.2 MB/tick through the coherence point; that
//   (plus store-queue stall, VALUBusy 31.6->24) ate the read-halving gain.
//   Fix: batch-half-major activation layout [slot][bh][512][32]:
//   - WG's 8 cols x 32 b = contiguous 1KB block; cell/inp stores from
//     threads 0..255 are consecutive addresses -> full-wave 256B
//     write-combining restored (WRITE back to ~447 KB/tick).
//   - gemv reads own half as 1KB-contiguous per wave per chunk (denser L2).
//   - out_block h1 gather stride 256B->128B (cached reads, harmless).
//   Everything else identical to R10 (ownership, LDS weights C17, 2-pass
//   reduction, 8-deep rotation, 7-periodic fence, arrive/wait window,
//   monotonic padded barrier, sc0sc1 write-through stores).

namespace {
constexpr int T_STEPS = 1024;
constexpr int B = 64;
constexpr int I_DIM = 128;
constexpr int H = 512;
constexpr int NBLK = 256;
constexpr int NTHR = 512;
constexpr int HB = H * B;   // 32768 floats = 128 KB (both halves)
constexpr int HSZ = H * 32; // 16384 floats = one batch half
constexpr int NSLOT = 8;    // rotation depth
constexpr int C17 = 17;     // padded chunk dim (K/64 = 16, +1 pad)
constexpr int RPAD = 36;    // padded 32-batch row stride in s_red2 (floats)

// ws layout (floats): 3 rotated streams + biases + barrier
constexpr int OFF_INP  = 0;                      // [8][2][512][32]
constexpr int OFF_H0   = OFF_INP + NSLOT * HB;   // [8][2][512][32]
constexpr int OFF_H1   = OFF_H0 + NSLOT * HB;    // [8][2][512][32]
constexpr int OFF_BSUM = OFF_H1 + NSLOT * HB;    // [2][2048] b_ih+b_hh
constexpr int OFF_BAR  = OFF_BSUM + 2 * 4 * H;   // barrier state
// barrier slots, stride 64 uints (256B): [0..15] group arrivals,
// [16] master, [17..32] per-group release flags, [33] poison
constexpr int BAR_SLOTS = 34;
constexpr int BAR_UINTS = BAR_SLOTS * 64;  // 2176
}  // namespace

typedef float f32x4 __attribute__((ext_vector_type(4)));

// coherent write-through store (sc0 sc1): lands at the coherence point,
// no dirty L2 line anywhere.
__device__ __forceinline__ void coh_store1(float* p, float v) {
  asm volatile("global_store_dword %0, %1, off sc0 sc1" ::"v"(p), "v"(v)
               : "memory");
}

__global__ __launch_bounds__(NTHR) void init_ws_kernel(
    float* __restrict__ ws, const float* __restrict__ b_ih,
    const float* __restrict__ b_hh) {
  int idx = blockIdx.x * blockDim.x + threadIdx.x;
  for (int f = idx; f < OFF_BSUM; f += NBLK * NTHR) coh_store1(ws + f, 0.f);
  if (idx < 2 * 4 * H) coh_store1(ws + OFF_BSUM + idx, b_ih[idx] + b_hh[idx]);
  if (idx < BAR_UINTS) coh_store1(ws + OFF_BAR + idx, 0.f);  // bits == 0u
}

__device__ __forceinline__ float sigm(float x) {
  return 1.f / (1.f + __expf(-x));
}
__device__ __forceinline__ float tanh_fast(float x) {
  float e = __expf(-2.f * fabsf(x));
  float t = (1.f - e) / (1.f + e);
  return x < 0.f ? -t : t;
}

__global__ __launch_bounds__(NTHR, 1) void lstm_kernel(
    const float* __restrict__ x, const float* __restrict__ w_in,
    const float* __restrict__ b_in, const float* __restrict__ w_ih,
    const float* __restrict__ w_hh, const float* __restrict__ w_out,
    const float* __restrict__ b_out, float* __restrict__ ws,
    float* __restrict__ out) {
  __shared__ float s_w[32 * 64 * C17];   // 139,264 B persistent gate weights
  __shared__ float s_red2[4][32 * RPAD]; // 18,432 B 2-pass reduction matrix
  __shared__ float s_g[1024];            // 4 KB gate pre-activations
  // aliases (s_red2 is free outside the gemv reduction):
  float* const s_h1p = &s_red2[0][0];    // 512 floats: gathered h1 column
  float* const s_op  = &s_red2[1][0];    // 512 floats: out partials

  const int tid = threadIdx.x;
  const int wg = blockIdx.x;
  const int layer = wg & 1;
  const int grp = wg >> 1;       // 0..127
  const int colgrp = grp >> 1;   // 0..63: owns h-cols colgrp*8 .. +7
  const int bh = grp & 1;        // batch half: b in [bh*32, bh*32+32)
  const size_t hoff = (size_t)bh * HSZ;  // offset of own half in a slot
  unsigned* const bar = reinterpret_cast<unsigned*>(ws + OFF_BAR);

  // ---- persistent weight load: s_w[(r*64+ss)*C17 + c] = W[layer][grow][k],
  //      r = q*8+j (q=gate, j=col-within-8), grow = q*512 + colgrp*8 + j,
  //      k = c*64 + ss (K-concat: k<512 -> w_ih, else w_hh) ----
#pragma unroll
  for (int i = 0; i < 16; ++i) {
    int idx = i * 512 + tid;  // float4 unit 0..8191
    int r = idx >> 8;         // 0..31
    int k0 = (idx & 255) * 4;
    int grow = (r >> 3) * 512 + colgrp * 8 + (r & 7);
    const float* srcp =
        (k0 < 512) ? (w_ih + ((size_t)layer * 4 * H + grow) * H + k0)
                   : (w_hh + ((size_t)layer * 4 * H + grow) * H + (k0 - 512));
    float4 v = *reinterpret_cast<const float4*>(srcp);
    float arr[4] = {v.x, v.y, v.z, v.w};
#pragma unroll
    for (int j = 0; j < 4; ++j) {
      int k = k0 + j;
      int c = k >> 6, ss = k & 63;
      s_w[(r * 64 + ss) * C17 + c] = arr[j];
    }
  }
  __syncthreads();

  // ---- split grid barrier: arrive (with optional pre-arrival L1+L2 inv),
  //      then window work, then wait ----
  unsigned bar_gen = 0;
  auto bar_arrive = [&](bool inv_l2) {
    ++bar_gen;
    if (inv_l2 && tid < 64) {
      // agent acquire: s_waitcnt + buffer_inv (L1+L2). Completes before
      // this WG's arrival (syncthreads below drains wave0's vmcnt).
      __builtin_amdgcn_fence(__ATOMIC_ACQUIRE, "agent");
    }
    __syncthreads();  // drains vmcnt per wave: all sc0sc1 data stores are
                      // at the coherence point before the leader signs in
    if (tid == 0) {
      if (__hip_atomic_load(bar + 33 * 64, __ATOMIC_RELAXED,
                            __HIP_MEMORY_SCOPE_AGENT) == 0u) {
        const unsigned grp16 = (unsigned)wg & 15u;
        unsigned prev = __hip_atomic_fetch_add(
            bar + grp16 * 64, 1u, __ATOMIC_RELAXED, __HIP_MEMORY_SCOPE_AGENT);
        if ((prev & 15u) == 15u) {  // last of group (monotonic count)
          unsigned mprev = __hip_atomic_fetch_add(
              bar + 16 * 64, 1u, __ATOMIC_RELAXED, __HIP_MEMORY_SCOPE_AGENT);
          if ((mprev & 15u) == 15u) {  // last group: release everyone
#pragma unroll
            for (int g2 = 0; g2 < 16; ++g2)
              __hip_atomic_store(bar + (17 + g2) * 64, bar_gen,
                                 __ATOMIC_RELAXED, __HIP_MEMORY_SCOPE_AGENT);
          }
        }
      }
    }
  };
  auto bar_wait = [&]() {
    if (tid == 0) {
      if (__hip_atomic_load(bar + 33 * 64, __ATOMIC_RELAXED,
                            __HIP_MEMORY_SCOPE_AGENT) == 0u) {
        const unsigned grp16 = (unsigned)wg & 15u;
        unsigned spin = 0;
        while (__hip_atomic_load(bar + (17 + grp16) * 64, __ATOMIC_RELAXED,
                                 __HIP_MEMORY_SCOPE_AGENT) < bar_gen) {
          __builtin_amdgcn_s_sleep(1);
          if ((++spin & 255u) == 0u) {
            if (__hip_atomic_load(bar + 33 * 64, __ATOMIC_RELAXED,
                                  __HIP_MEMORY_SCOPE_AGENT) != 0u)
              break;
            if (spin > (1u << 19)) {  // failsafe: fast-fail, don't hang
              __hip_atomic_store(bar + 33 * 64, 1u, __ATOMIC_RELAXED,
                                 __HIP_MEMORY_SCOPE_AGENT);
              break;
            }
          }
        }
      }
    }
    __syncthreads();
    // no per-tick cache maintenance (R9 result); staleness covered by the
    // 7-periodic agent fence (reuse distance 8 for all streams).
    asm volatile("" ::: "memory");
  };

  // ---- gates gemv: 32 rows x 32 b (own half), K=1024 = [lo;hi], k-major.
  //      lo/hi point at this WG's bh half: [512 k][32 b]. Each wave reads
  //      1KB contiguous per chunk slice; 16 f32x4 loads/thread (128 KB/WG).
  auto gemv = [&](const float* __restrict__ lo, const float* __restrict__ hi) {
    const int s = tid >> 3;              // k-slice 0..63 (k = c*64 + s)
    const int tq = tid & 7;              // batch quad within the half
    const int abase = s * 32 + tq * 4;
    float acc[128];                      // [row 0..31][bb 0..3]
#pragma unroll
    for (int q = 0; q < 128; ++q) acc[q] = 0.f;

    f32x4 a_cur[4], a_nxt[4];
#pragma unroll
    for (int c = 0; c < 4; ++c)
      a_cur[c] = *reinterpret_cast<const f32x4*>(lo + c * 2048 + abase);
#pragma unroll
    for (int g = 0; g < 4; ++g) {
      if (g < 3) {
#pragma unroll
        for (int cc = 0; cc < 4; ++cc) {
          const int c = (g + 1) * 4 + cc;
          const float* p =
              (c < 8 ? lo + c * 2048 : hi + (c - 8) * 2048) + abase;
          a_nxt[cc] = *reinterpret_cast<const f32x4*>(p);
        }
      }
      // rows in quarters of 8 to cap live wr[] registers
#pragma unroll
      for (int rh = 0; rh < 4; ++rh) {
        float4 wr[8];
#pragma unroll
        for (int r8 = 0; r8 < 8; ++r8)
          wr[r8] = *reinterpret_cast<const float4*>(
              &s_w[((rh * 8 + r8) * 64 + s) * C17 + g * 4]);
#pragma unroll
        for (int cc = 0; cc < 4; ++cc) {
          const float a0 = a_cur[cc].x, a1 = a_cur[cc].y, a2 = a_cur[cc].z,
                      a3 = a_cur[cc].w;
#pragma unroll
          for (int r8 = 0; r8 < 8; ++r8) {
            const float w = (cc == 0)   ? wr[r8].x
                            : (cc == 1) ? wr[r8].y
                            : (cc == 2) ? wr[r8].z
                                        : wr[r8].w;
            const int ab = (rh * 8 + r8) * 4;
            acc[ab + 0] = fmaf(w, a0, acc[ab + 0]);
            acc[ab + 1] = fmaf(w, a1, acc[ab + 1]);
            acc[ab + 2] = fmaf(w, a2, acc[ab + 2]);
            acc[ab + 3] = fmaf(w, a3, acc[ab + 3]);
          }
        }
      }
      if (g < 3) {
#pragma unroll
        for (int cc = 0; cc < 4; ++cc) a_cur[cc] = a_nxt[cc];
      }
    }

    // ---- exchange-and-halve reduction over lane bits 3..5 (s&7) ----
    const int lane = tid & 63;
    const bool b3 = (lane & 8) != 0;
    const bool b4 = (lane & 16) != 0;
    const bool b5 = (lane & 32) != 0;
    float v1[64];
#pragma unroll
    for (int go = 0; go < 16; ++go)
#pragma unroll
      for (int bb = 0; bb < 4; ++bb) {
        float lc = acc[(2 * go + 0) * 4 + bb];
        float hc = acc[(2 * go + 1) * 4 + bb];
        float lo_o = __shfl_xor(lc, 8, 64);
        float hi_o = __shfl_xor(hc, 8, 64);
        v1[go * 4 + bb] = b3 ? (hc + hi_o) : (lc + lo_o);
      }
    float v2[32];
#pragma unroll
    for (int go = 0; go < 8; ++go)
#pragma unroll
      for (int bb = 0; bb < 4; ++bb) {
        float lc = v1[(2 * go + 0) * 4 + bb];
        float hc = v1[(2 * go + 1) * 4 + bb];
        float lo_o = __shfl_xor(lc, 16, 64);
        float hi_o = __shfl_xor(hc, 16, 64);
        v2[go * 4 + bb] = b4 ? (hc + hi_o) : (lc + lo_o);
      }
    float fin[16];
#pragma unroll
    for (int go = 0; go < 4; ++go)
#pragma unroll
      for (int bb = 0; bb < 4; ++bb) {
        float lc = v2[(2 * go + 0) * 4 + bb];
        float hc = v2[(2 * go + 1) * 4 + bb];
        float lo_o = __shfl_xor(lc, 32, 64);
        float hi_o = __shfl_xor(hc, 32, 64);
        fin[go * 4 + bb] = b5 ? (hc + hi_o) : (lc + lo_o);
      }
    // lane (sigma = (lane>>3)&7, tq) holds rows {sigma, 8+s, 16+s, 24+s},
    // batch quad tq. 2-pass cross-wave sum: waves 0-3 write, 4-7 RMW.
    const int wv = tid >> 6;
    const int sigma = (lane >> 3) & 7;
    if (wv < 4) {
#pragma unroll
      for (int go = 0; go < 4; ++go)
        *reinterpret_cast<float4*>(
            &s_red2[wv][(go * 8 + sigma) * RPAD + tq * 4]) =
            make_float4(fin[go * 4 + 0], fin[go * 4 + 1], fin[go * 4 + 2],
                        fin[go * 4 + 3]);
    }
    __syncthreads();
    if (wv >= 4) {
#pragma unroll
      for (int go = 0; go < 4; ++go) {
        float4* p = reinterpret_cast<float4*>(
            &s_red2[wv - 4][(go * 8 + sigma) * RPAD + tq * 4]);
        float4 o = *p;
        *p = make_float4(o.x + fin[go * 4 + 0], o.y + fin[go * 4 + 1],
                         o.z + fin[go * 4 + 2], o.w + fin[go * 4 + 3]);
      }
    }
    __syncthreads();
    {
      const float* bsum_l = ws + OFF_BSUM + layer * 2048;
#pragma unroll
      for (int h2 = 0; h2 < 2; ++h2) {
        int o = h2 * 512 + tid;     // 0..1023 = row*32 + bl
        int row = o >> 5, bl = o & 31;
        int pidx = row * RPAD + bl;
        float sum = s_red2[0][pidx] + s_red2[1][pidx] + s_red2[2][pidx] +
                    s_red2[3][pidx];
        int grow = (row >> 3) * 512 + colgrp * 8 + (row & 7);
        s_g[o] = sum + bsum_l[grow];  // s_g[row*32 + bl]
      }
    }
    __syncthreads();
  };

  float cs = 0.f;  // tid<256 owns (col = colgrp*8 + tid>>5, bl = tid&31)

  // dst_half points at [slot][bh] half base; WG's block is contiguous 1KB:
  // addr = col*32 + bl = colgrp*256 + tid  (threads 0..255 consecutive).
  auto cell_update = [&](float* dst_half) {
    if (tid < 256) {
      const int j = tid >> 5, bl = tid & 31;
      float ig = sigm(s_g[(0 * 8 + j) * 32 + bl]);
      float fg = sigm(s_g[(1 * 8 + j) * 32 + bl]);
      float gt = tanh_fast(s_g[(2 * 8 + j) * 32 + bl]);
      float og = sigm(s_g[(3 * 8 + j) * 32 + bl]);
      cs = fg * cs + ig * gt;
      coh_store1(dst_half + colgrp * 256 + tid, og * tanh_fast(cs));
    }
  };

  // ---- inp(tn): per-thread dot (no LDS, no syncs — pure window work).
  //      Stores contiguous into own half block. ----
  auto inp_block = [&](int tn, int slot) {
    if (tid < 256) {
      const int j = tid >> 5, bl = tid & 31;
      const int col = colgrp * 8 + j, b = bh * 32 + bl;
      const float* xsrc = x + ((size_t)tn * B + b) * I_DIM;
      const float* wrow = w_in + (size_t)col * I_DIM;
      float part = 0.f;
#pragma unroll
      for (int k4 = 0; k4 < 32; ++k4) {
        float4 xv = *reinterpret_cast<const float4*>(xsrc + k4 * 4);
        float4 wv = *reinterpret_cast<const float4*>(wrow + k4 * 4);
        part += xv.x * wv.x + xv.y * wv.y + xv.z * wv.z + xv.w * wv.w;
      }
      coh_store1(ws + OFF_INP + (size_t)slot * HB + hoff + colgrp * 256 + tid,
                 sigm(part + b_in[col]));
    }
  };

  // ---- out(tt): gather h1 column b into LDS once, then reduce.
  //      L1 WGs only: b = colgrp (0..63), i-half = bh. ----
  auto out_block = [&](int tt, int slot) {
    const int b = colgrp, ihalf = bh;
    s_h1p[tid] = ws[OFF_H1 + (size_t)slot * HB + (size_t)(b >> 5) * HSZ +
                    tid * 32 + (b & 31)];  // cached gather, stride 128B
    __syncthreads();
    const int io = tid & 63, ks = tid >> 6;  // ks 0..7, 64 k each
    const int i = ihalf * 64 + io;
    const float* wrow = w_out + (size_t)i * H + ks * 64;
    const float* hl = s_h1p + ks * 64;  // broadcast across io lanes
    float part = 0.f;
#pragma unroll
    for (int k4 = 0; k4 < 16; ++k4) {
      float4 wv = *reinterpret_cast<const float4*>(wrow + k4 * 4);
      part += wv.x * hl[k4 * 4 + 0] + wv.y * hl[k4 * 4 + 1] +
              wv.z * hl[k4 * 4 + 2] + wv.w * hl[k4 * 4 + 3];
    }
    s_op[tid] = part;
    __syncthreads();
    if (tid < 64) {
      float sum = 0.f;
#pragma unroll
      for (int kk = 0; kk < 8; ++kk) sum += s_op[kk * 64 + tid];
      const int ii = ihalf * 64 + tid;
      coh_store1(out + ((size_t)tt * B + b) * I_DIM + ii, sum + b_out[ii]);
    }
    __syncthreads();
  };

  // ---------------- prologue: inp(0), inp(1); barrier B0 (inv) ----------
  if (layer == 0) {
    inp_block(0, 0);
    inp_block(1, 1);
  }
  bar_arrive(true);  // B0: inv barrier (also kills pre-launch stale lines)
  bar_wait();

  // ---------------- pipelined main loop: one barrier per tick -----------
  // tick tau: L0 computes h0(tau); L1 computes h1(tau-1). Window work
  // (between arrive and wait): L0 writes inp(tau+2), L1 writes out(tau-2).
  // Barrier after tick tau is B_{tau+1}; inv when (tau+1)%7==0.
  for (int tau = 0; tau <= T_STEPS + 1; ++tau) {
    const int sl = tau & 7;
    const float* glo;
    const float* ghi;
    float* gdst;
    bool do_g;
    if (layer == 0) {
      glo = ws + OFF_INP + (size_t)sl * HB + hoff;             // inp(tau)
      ghi = ws + OFF_H0 + (size_t)((tau - 1) & 7) * HB + hoff; // h0(tau-1)
      gdst = ws + OFF_H0 + (size_t)sl * HB + hoff;             // h0(tau)
      do_g = (tau < T_STEPS);
    } else {
      glo = ws + OFF_H0 + (size_t)((tau - 1) & 7) * HB + hoff; // h0(tau-1)
      ghi = ws + OFF_H1 + (size_t)((tau - 2) & 7) * HB + hoff; // h1(tau-2)
      gdst = ws + OFF_H1 + (size_t)((tau - 1) & 7) * HB + hoff;// h1(tau-1)
      do_g = (tau >= 1 && tau <= T_STEPS);
    }
    if (do_g) {
      gemv(glo, ghi);
      cell_update(gdst);
    }
    if (tau <= T_STEPS) {
      bar_arrive(((tau + 1) % 7) == 0);
      // ---- window work (post-arrival, pre-release) ----
      if (layer == 0) {
        if (tau + 2 <= T_STEPS - 1) inp_block(tau + 2, (tau + 2) & 7);
      } else {
        if (tau >= 2) out_block(tau - 2, (tau - 2) & 7);
      }
      bar_wait();
    } else {
      // final tick (tau == T_STEPS+1): no barrier; L1 emits last output
      if (layer == 1) out_block(tau - 2, (tau - 2) & 7);
    }
  }
}

extern "C" void kernel_launch(void* const* d_in, const int* in_sizes, int n_in,
                              void* d_out, int out_size, void* d_ws,
                              size_t ws_size, hipStream_t stream) {
  const float* x     = (const float*)d_in[0];
  const float* w_in  = (const float*)d_in[1];
  const float* b_in  = (const float*)d_in[2];
  const float* w_ih  = (const float*)d_in[3];
  const float* w_hh  = (const float*)d_in[4];
  const float* b_ih  = (const float*)d_in[5];
  const float* b_hh  = (const float*)d_in[6];
  const float* w_out = (const float*)d_in[7];
  const float* b_out = (const float*)d_in[8];
  float* ws   = (float*)d_ws;
  float* outp = (float*)d_out;

  hipLaunchKernelGGL(init_ws_kernel, dim3(NBLK), dim3(NTHR), 0, stream, ws,
                     b_ih, b_hh);
  hipLaunchKernelGGL(lstm_kernel, dim3(NBLK), dim3(NTHR), 0, stream, x, w_in,
                     b_in, w_ih, w_hh, w_out, b_out, ws, outp);
}

// Round 8
// 19321.835 us; speedup vs baseline: 1.2975x; 1.2975x over previous
//
#include <hip/hip_runtime.h>
#include <math.h>

// LSTMNN: T=1024, B=64, I=128, H=512, L=2, fp32. Persistent 256 WG x 512 thr.
// Round 12: REVERT to R9 (best-known, 17.26 ms) + chunk-phase rotation.
//   R10/R11 (batch-split ownership) both regressed with inconsistent
//   counter signatures (R10 WRITE 8x; R11 WRITE 6x AND FETCH 4x despite
//   contiguous stores) -> branch abandoned.
//   Standing mystery in R9: zero per-tick invalidation, yet panel reads
//   behave as unique-per-WG MALL streams (~3.6 TB/s law). Per XCD, ~16
//   same-layer WGs read the IDENTICAL 256 KB panel; if L2 allocation
//   worked, 15/16 would hit L2. Hypotheses:
//     H1 temporal alignment: barrier releases all WGs simultaneously and
//        they march chunks 0->15 in lockstep -> all WGs miss each line in
//        the same window; no one ever reads an already-filled L2 line.
//     H2 sc0sc1-written data never allocates in L2 on read -> structural.
//   R12 discriminates: per-WG chunk-phase rotation rotg=(wg>>3)&3 (varies
//   WITHIN an XCD; (wg>>1)&3 would be per-XCD-constant since wg%8 fixes
//   the XCD). Group order (g+rotg)&3: phase-p WGs miss group p first;
//   other phases arrive ~us later -> should L2-hit if H1. Weight float4
//   loads stay 16B-aligned (rotation in multiples of 4 cols). Summation
//   order change ~1e-7. Everything else byte-identical to R9.

namespace {
constexpr int T_STEPS = 1024;
constexpr int B = 64;
constexpr int I_DIM = 128;
constexpr int H = 512;
constexpr int NBLK = 256;
constexpr int NTHR = 512;
constexpr int HB = H * B;   // 32768 floats = 128 KB
constexpr int NSLOT = 8;    // rotation depth
constexpr int P = 20;       // padded chunk dim for LDS weights

// ws layout (floats): 3 rotated streams + biases + barrier
constexpr int OFF_INP  = 0;                      // [8][512][64]
constexpr int OFF_H0   = OFF_INP + NSLOT * HB;   // [8][512][64]
constexpr int OFF_H1   = OFF_H0 + NSLOT * HB;    // [8][512][64]
constexpr int OFF_BSUM = OFF_H1 + NSLOT * HB;    // [2][2048] b_ih+b_hh
constexpr int OFF_BAR  = OFF_BSUM + 2 * 4 * H;   // barrier state
// barrier slots, stride 64 uints (256B): [0..15] group arrivals,
// [16] master, [17..32] per-group release flags, [33] poison
constexpr int BAR_SLOTS = 34;
constexpr int BAR_UINTS = BAR_SLOTS * 64;  // 2176
}  // namespace

typedef float f32x4 __attribute__((ext_vector_type(4)));

// coherent write-through store (sc0 sc1): lands at the coherence point,
// no dirty L2 line anywhere.
__device__ __forceinline__ void coh_store1(float* p, float v) {
  asm volatile("global_store_dword %0, %1, off sc0 sc1" ::"v"(p), "v"(v)
               : "memory");
}

__global__ __launch_bounds__(NTHR) void init_ws_kernel(
    float* __restrict__ ws, const float* __restrict__ b_ih,
    const float* __restrict__ b_hh) {
  int idx = blockIdx.x * blockDim.x + threadIdx.x;
  for (int f = idx; f < OFF_BSUM; f += NBLK * NTHR) coh_store1(ws + f, 0.f);
  if (idx < 2 * 4 * H) coh_store1(ws + OFF_BSUM + idx, b_ih[idx] + b_hh[idx]);
  if (idx < BAR_UINTS) coh_store1(ws + OFF_BAR + idx, 0.f);  // bits == 0u
}

__device__ __forceinline__ float sigm(float x) {
  return 1.f / (1.f + __expf(-x));
}
__device__ __forceinline__ float tanh_fast(float x) {
  float e = __expf(-2.f * fabsf(x));
  float t = (1.f - e) / (1.f + e);
  return x < 0.f ? -t : t;
}

__global__ __launch_bounds__(NTHR, 2) void lstm_kernel(
    const float* __restrict__ x, const float* __restrict__ w_in,
    const float* __restrict__ b_in, const float* __restrict__ w_ih,
    const float* __restrict__ w_hh, const float* __restrict__ w_out,
    const float* __restrict__ b_out, float* __restrict__ ws,
    float* __restrict__ out) {
  __shared__ float s_w[16 * 64 * P];  // 80 KB persistent gate weights
  __shared__ float s_red[8 * 1024];   // 32 KB reduction scratch
  __shared__ float s_g[1024];         // 4 KB gate pre-activations
  __shared__ float s_h1[512];         // 2 KB gathered h1 column (out)

  const int tid = threadIdx.x;
  const int wg = blockIdx.x;
  const int layer = wg & 1;
  const int lid = wg >> 1;  // 0..127: owns h-columns lid*4 .. +3
  unsigned* const bar = reinterpret_cast<unsigned*>(ws + OFF_BAR);

  // ---- persistent weight load: s_w[(r*64+ss)*P + c] = W[layer][grow][k],
  //      r = q*4+j (q=gate, j=col-within-4), grow = q*512 + lid*4 + j,
  //      k = c*64 + ss (K-concat: k<512 -> w_ih, else w_hh) ----
#pragma unroll
  for (int i = 0; i < 8; ++i) {
    int idx = i * 512 + tid;  // float4 unit 0..4095
    int r = idx >> 8;         // 0..15
    int k0 = (idx & 255) * 4;
    int grow = (r >> 2) * 512 + lid * 4 + (r & 3);
    const float* srcp =
        (k0 < 512) ? (w_ih + ((size_t)layer * 4 * H + grow) * H + k0)
                   : (w_hh + ((size_t)layer * 4 * H + grow) * H + (k0 - 512));
    float4 v = *reinterpret_cast<const float4*>(srcp);
    float arr[4] = {v.x, v.y, v.z, v.w};
#pragma unroll
    for (int j = 0; j < 4; ++j) {
      int k = k0 + j;
      int c = k >> 6, ss = k & 63;
      s_w[(r * 64 + ss) * P + c] = arr[j];
    }
  }
  __syncthreads();

  // ---- split grid barrier: arrive (with optional pre-arrival L1+L2 inv),
  //      then window work, then wait ----
  unsigned bar_gen = 0;
  auto bar_arrive = [&](bool inv_l2) {
    ++bar_gen;
    if (inv_l2 && tid < 64) {
      // agent acquire: s_waitcnt + buffer_inv (L1+L2). Completes before
      // this WG's arrival (syncthreads below drains wave0's vmcnt).
      __builtin_amdgcn_fence(__ATOMIC_ACQUIRE, "agent");
    }
    __syncthreads();  // drains vmcnt per wave: all sc0sc1 data stores are
                      // at the coherence point before the leader signs in
    if (tid == 0) {
      if (__hip_atomic_load(bar + 33 * 64, __ATOMIC_RELAXED,
                            __HIP_MEMORY_SCOPE_AGENT) == 0u) {
        const unsigned grp = (unsigned)wg & 15u;
        unsigned prev = __hip_atomic_fetch_add(
            bar + grp * 64, 1u, __ATOMIC_RELAXED, __HIP_MEMORY_SCOPE_AGENT);
        if ((prev & 15u) == 15u) {  // last of group (monotonic count)
          unsigned mprev = __hip_atomic_fetch_add(
              bar + 16 * 64, 1u, __ATOMIC_RELAXED, __HIP_MEMORY_SCOPE_AGENT);
          if ((mprev & 15u) == 15u) {  // last group: release everyone
#pragma unroll
            for (int g2 = 0; g2 < 16; ++g2)
              __hip_atomic_store(bar + (17 + g2) * 64, bar_gen,
                                 __ATOMIC_RELAXED, __HIP_MEMORY_SCOPE_AGENT);
          }
        }
      }
    }
  };
  auto bar_wait = [&]() {
    if (tid == 0) {
      if (__hip_atomic_load(bar + 33 * 64, __ATOMIC_RELAXED,
                            __HIP_MEMORY_SCOPE_AGENT) == 0u) {
        const unsigned grp = (unsigned)wg & 15u;
        unsigned spin = 0;
        while (__hip_atomic_load(bar + (17 + grp) * 64, __ATOMIC_RELAXED,
                                 __HIP_MEMORY_SCOPE_AGENT) < bar_gen) {
          __builtin_amdgcn_s_sleep(1);
          if ((++spin & 255u) == 0u) {
            if (__hip_atomic_load(bar + 33 * 64, __ATOMIC_RELAXED,
                                  __HIP_MEMORY_SCOPE_AGENT) != 0u)
              break;
            if (spin > (1u << 19)) {  // failsafe: fast-fail, don't hang
              __hip_atomic_store(bar + 33 * 64, 1u, __ATOMIC_RELAXED,
                                 __HIP_MEMORY_SCOPE_AGENT);
              break;
            }
          }
        }
      }
    }
    __syncthreads();
    // no per-tick cache maintenance (R9 result); staleness covered by the
    // 7-periodic agent fence (reuse distance 8 for all streams).
    asm volatile("" ::: "memory");
  };

  // ---- gates gemv: 16 rows x 64 b, K=1024 = [lo(512);hi(512)], k-major.
  //      Chunk-group order rotated by rotg so co-XCD WGs desynchronize
  //      their miss streams (L2-reuse probe). ----
  const int rotg = (wg >> 3) & 3;  // varies across the 32 WGs of an XCD
  auto gemv = [&](const float* __restrict__ lo, const float* __restrict__ hi) {
    const int s = tid >> 3;  // k-slice 0..63
    const int tb = tid & 7;  // batch octet
    const int abase = s * 64 + tb * 8;
    float acc[128];
#pragma unroll
    for (int q = 0; q < 128; ++q) acc[q] = 0.f;

    f32x4 a_cur[4][2], a_nxt[4][2];
    {
      const int cb0 = rotg * 4;
#pragma unroll
      for (int cc = 0; cc < 4; ++cc) {
        const int c = cb0 + cc;
        const float* p =
            (c < 8 ? lo + c * 4096 : hi + (c - 8) * 4096) + abase;
        a_cur[cc][0] = *reinterpret_cast<const f32x4*>(p);
        a_cur[cc][1] = *reinterpret_cast<const f32x4*>(p + 4);
      }
    }
#pragma unroll
    for (int g = 0; g < 4; ++g) {
      const int cbase = ((g + rotg) & 3) * 4;  // weight col base this group
      if (g < 3) {
        const int cbn = ((g + 1 + rotg) & 3) * 4;
#pragma unroll
        for (int cc = 0; cc < 4; ++cc) {
          const int c = cbn + cc;
          const float* p =
              (c < 8 ? lo + c * 4096 : hi + (c - 8) * 4096) + abase;
          a_nxt[cc][0] = *reinterpret_cast<const f32x4*>(p);
          a_nxt[cc][1] = *reinterpret_cast<const f32x4*>(p + 4);
        }
      }
      // rows in two halves of 8 to cap live wr[] registers
#pragma unroll
      for (int rh = 0; rh < 2; ++rh) {
        float4 wr[8];
#pragma unroll
        for (int r8 = 0; r8 < 8; ++r8)
          wr[r8] = *reinterpret_cast<const float4*>(
              &s_w[((rh * 8 + r8) * 64 + s) * P + cbase]);
#pragma unroll
        for (int cc = 0; cc < 4; ++cc) {
          float av[8] = {a_cur[cc][0].x, a_cur[cc][0].y, a_cur[cc][0].z,
                         a_cur[cc][0].w, a_cur[cc][1].x, a_cur[cc][1].y,
                         a_cur[cc][1].z, a_cur[cc][1].w};
#pragma unroll
          for (int r8 = 0; r8 < 8; ++r8) {
            float w = (cc == 0)   ? wr[r8].x
                      : (cc == 1) ? wr[r8].y
                      : (cc == 2) ? wr[r8].z
                                  : wr[r8].w;
#pragma unroll
            for (int bb = 0; bb < 8; ++bb)
              acc[(rh * 8 + r8) * 8 + bb] =
                  fmaf(w, av[bb], acc[(rh * 8 + r8) * 8 + bb]);
          }
        }
      }
      if (g < 3) {
#pragma unroll
        for (int cc = 0; cc < 4; ++cc) {
          a_cur[cc][0] = a_nxt[cc][0];
          a_cur[cc][1] = a_nxt[cc][1];
        }
      }
    }

    // ---- exchange-and-halve reduction over lane bits 3..5 ----
    const int lane = tid & 63;
    const bool b3 = (lane & 8) != 0;
    const bool b4 = (lane & 16) != 0;
    const bool b5 = (lane & 32) != 0;
    float v1[64];
#pragma unroll
    for (int go = 0; go < 8; ++go)
#pragma unroll
      for (int j = 0; j < 8; ++j) {
        float lc = acc[(2 * go + 0) * 8 + j];
        float hc = acc[(2 * go + 1) * 8 + j];
        float lo_o = __shfl_xor(lc, 8, 64);
        float hi_o = __shfl_xor(hc, 8, 64);
        v1[go * 8 + j] = b3 ? (hc + hi_o) : (lc + lo_o);
      }
    float v2[32];
#pragma unroll
    for (int go = 0; go < 4; ++go)
#pragma unroll
      for (int j = 0; j < 8; ++j) {
        float lc = v1[(2 * go + 0) * 8 + j];
        float hc = v1[(2 * go + 1) * 8 + j];
        float lo_o = __shfl_xor(lc, 16, 64);
        float hi_o = __shfl_xor(hc, 16, 64);
        v2[go * 8 + j] = b4 ? (hc + hi_o) : (lc + lo_o);
      }
    float fin[16];
#pragma unroll
    for (int go = 0; go < 2; ++go)
#pragma unroll
      for (int j = 0; j < 8; ++j) {
        float lc = v2[(2 * go + 0) * 8 + j];
        float hc = v2[(2 * go + 1) * 8 + j];
        float lo_o = __shfl_xor(lc, 32, 64);
        float hi_o = __shfl_xor(hc, 32, 64);
        fin[go * 8 + j] = b5 ? (hc + hi_o) : (lc + lo_o);
      }
    // lane holds rows {sigma, 8+sigma} for b = tb*8 + j
    const int wv = tid >> 6;
    const int sigma = (lane >> 3) & 7;
    float* dst0 = s_red + wv * 1024 + sigma * 64 + tb * 8;
    *reinterpret_cast<float4*>(dst0) =
        make_float4(fin[0], fin[1], fin[2], fin[3]);
    *reinterpret_cast<float4*>(dst0 + 4) =
        make_float4(fin[4], fin[5], fin[6], fin[7]);
    float* dst1 = dst0 + 512;  // rows 8+sigma
    *reinterpret_cast<float4*>(dst1) =
        make_float4(fin[8], fin[9], fin[10], fin[11]);
    *reinterpret_cast<float4*>(dst1 + 4) =
        make_float4(fin[12], fin[13], fin[14], fin[15]);
    __syncthreads();
    {
      const float* bsum_l = ws + OFF_BSUM + layer * 2048;
#pragma unroll
      for (int h2 = 0; h2 < 2; ++h2) {
        int o = h2 * 512 + tid;
        float sum = 0.f;
#pragma unroll
        for (int w8 = 0; w8 < 8; ++w8) sum += s_red[w8 * 1024 + o];
        int r = o >> 6;
        int grow = (r >> 2) * 512 + lid * 4 + (r & 3);
        s_g[o] = sum + bsum_l[grow];  // s_g[r*64 + b]
      }
    }
    __syncthreads();
  };

  float cs = 0.f;  // tid<256 owns cell state (col = lid*4 + (tid>>6), b)

  auto cell_update = [&](float* dst) {
    if (tid < 256) {
      const int j = tid >> 6, b = tid & 63, col = lid * 4 + j;
      float ig = sigm(s_g[j * 64 + b]);
      float fg = sigm(s_g[(4 + j) * 64 + b]);
      float gt = tanh_fast(s_g[(8 + j) * 64 + b]);
      float og = sigm(s_g[(12 + j) * 64 + b]);
      cs = fg * cs + ig * gt;
      coh_store1(dst + col * 64 + b, og * tanh_fast(cs));
    }
  };

  // ---- inp(tn) = sigmoid(x[tn] @ w_in^T + b_in) -> cols lid*4..+3 ----
  auto inp_block = [&](int tn, int slot) {
    const int b = tid & 63, jj = (tid >> 6) & 3, kh = tid >> 8;
    const int col = lid * 4 + jj;
    const float* xsrc = x + ((size_t)tn * B + b) * I_DIM + kh * 64;
    const float* wrow = w_in + (size_t)col * I_DIM + kh * 64;
    float part = 0.f;
#pragma unroll
    for (int k4 = 0; k4 < 16; ++k4) {
      float4 xv = *reinterpret_cast<const float4*>(xsrc + k4 * 4);
      float4 wv = *reinterpret_cast<const float4*>(wrow + k4 * 4);
      part += xv.x * wv.x + xv.y * wv.y + xv.z * wv.z + xv.w * wv.w;
    }
    s_red[tid] = part;
    __syncthreads();
    if (tid < 256) {
      float v = s_red[tid] + s_red[tid + 256];
      const int jj2 = (tid >> 6) & 3, b2 = tid & 63;
      const int col2 = lid * 4 + jj2;
      coh_store1(ws + OFF_INP + (size_t)slot * HB + col2 * 64 + b2,
                 sigm(v + b_in[col2]));
    }
    __syncthreads();
  };

  // ---- out(tt): gather h1 column b into LDS once, then reduce ----
  auto out_block = [&](int tt, int slot) {
    const int b = lid >> 1, ihalf = lid & 1;
    s_h1[tid] = ws[OFF_H1 + (size_t)slot * HB + tid * 64 + b];  // cached
    __syncthreads();
    const int io = tid & 63, ks = tid >> 6;  // ks 0..7, 64 k each
    const int i = ihalf * 64 + io;
    const float* wrow = w_out + (size_t)i * H + ks * 64;
    const float* hl = s_h1 + ks * 64;  // broadcast across io lanes
    float part = 0.f;
#pragma unroll
    for (int k4 = 0; k4 < 16; ++k4) {
      float4 wv = *reinterpret_cast<const float4*>(wrow + k4 * 4);
      part += wv.x * hl[k4 * 4 + 0] + wv.y * hl[k4 * 4 + 1] +
              wv.z * hl[k4 * 4 + 2] + wv.w * hl[k4 * 4 + 3];
    }
    s_red[tid] = part;
    __syncthreads();
    if (tid < 64) {
      float sum = 0.f;
#pragma unroll
      for (int kk = 0; kk < 8; ++kk) sum += s_red[kk * 64 + tid];
      const int ii = ihalf * 64 + tid;
      coh_store1(out + ((size_t)tt * B + b) * I_DIM + ii, sum + b_out[ii]);
    }
    __syncthreads();
  };

  // ---------------- prologue: inp(0), inp(1); barrier B0 (inv) ----------
  if (layer == 0) {
    inp_block(0, 0);
    inp_block(1, 1);
  }
  bar_arrive(true);  // B0: inv barrier (also kills pre-launch stale lines)
  bar_wait();

  // ---------------- pipelined main loop: one barrier per tick -----------
  // tick tau: L0 computes h0(tau); L1 computes h1(tau-1). Window work
  // (between arrive and wait): L0 writes inp(tau+2), L1 writes out(tau-2).
  // Barrier after tick tau is B_{tau+1}; inv when (tau+1)%7==0.
  for (int tau = 0; tau <= T_STEPS + 1; ++tau) {
    const int sl = tau & 7;
    const float* glo;
    const float* ghi;
    float* gdst;
    bool do_g;
    if (layer == 0) {
      glo = ws + OFF_INP + (size_t)sl * HB;                  // inp(tau)
      ghi = ws + OFF_H0 + (size_t)((tau - 1) & 7) * HB;      // h0(tau-1)
      gdst = ws + OFF_H0 + (size_t)sl * HB;                  // h0(tau)
      do_g = (tau < T_STEPS);
    } else {
      glo = ws + OFF_H0 + (size_t)((tau - 1) & 7) * HB;      // h0(tau-1)
      ghi = ws + OFF_H1 + (size_t)((tau - 2) & 7) * HB;      // h1(tau-2)
      gdst = ws + OFF_H1 + (size_t)((tau - 1) & 7) * HB;     // h1(tau-1)
      do_g = (tau >= 1 && tau <= T_STEPS);
    }
    if (do_g) {
      gemv(glo, ghi);
      cell_update(gdst);
    }
    if (tau <= T_STEPS) {
      bar_arrive(((tau + 1) % 7) == 0);
      // ---- window work (post-arrival, pre-release) ----
      if (layer == 0) {
        if (tau + 2 <= T_STEPS - 1) inp_block(tau + 2, (tau + 2) & 7);
      } else {
        if (tau >= 2) out_block(tau - 2, (tau - 2) & 7);
      }
      bar_wait();
    } else {
      // final tick (tau == T_STEPS+1): no barrier; L1 emits last output
      if (layer == 1) out_block(tau - 2, (tau - 2) & 7);
    }
  }
}

extern "C" void kernel_launch(void* const* d_in, const int* in_sizes, int n_in,
                              void* d_out, int out_size, void* d_ws,
                              size_t ws_size, hipStream_t stream) {
  const float* x     = (const float*)d_in[0];
  const float* w_in  = (const float*)d_in[1];
  const float* b_in  = (const float*)d_in[2];
  const float* w_ih  = (const float*)d_in[3];
  const float* w_hh  = (const float*)d_in[4];
  const float* b_ih  = (const float*)d_in[5];
  const float* b_hh  = (const float*)d_in[6];
  const float* w_out = (const float*)d_in[7];
  const float* b_out = (const float*)d_in[8];
  float* ws   = (float*)d_ws;
  float* outp = (float*)d_out;

  hipLaunchKernelGGL(init_ws_kernel, dim3(NBLK), dim3(NTHR), 0, stream, ws,
                     b_ih, b_hh);
  hipLaunchKernelGGL(lstm_kernel, dim3(NBLK), dim3(NTHR), 0, stream, x, w_in,
                     b_in, w_ih, w_hh, w_out, b_out, ws, outp);
}